// Round 1
// baseline (1022.345 us; speedup 1.0000x reference)
//
#include <hip/hip_runtime.h>

// Problem constants (from reference setup_inputs; n_steps==64 fixed for this instance).
#define BDIM 4096
#define DX 512
#define DZ 512
#define DY 256
#define HD 2048
#define NSTEPS 64

#define BM 64
#define BN 64
#define BK 16

// ---------------------------------------------------------------------------
// 32x32 LDS-tiled transpose: out[j][i] = in[i][j], D x D, D % 32 == 0.
__global__ __launch_bounds__(256) void transpose_k(const float* __restrict__ in,
                                                   float* __restrict__ out, int D) {
    __shared__ float t[32][33];
    const int bx = blockIdx.x * 32, by = blockIdx.y * 32;
    const int x = threadIdx.x, y = threadIdx.y;  // block (32,8)
#pragma unroll
    for (int dy = 0; dy < 32; dy += 8)
        t[y + dy][x] = in[(size_t)(by + y + dy) * D + bx + x];
    __syncthreads();
#pragma unroll
    for (int dy = 0; dy < 32; dy += 8)
        out[(size_t)(bx + y + dy) * D + by + x] = t[x][y + dy];
}

// ---------------------------------------------------------------------------
// Mstep = I + h*N + h^2/2*N2 + h^3/6*N3 + h^4/24*N4   (RK4 == Taylor-4 for linear f)
__global__ __launch_bounds__(256) void taylor_k(const float* __restrict__ N_,
                                                const float* __restrict__ P2,
                                                const float* __restrict__ P3,
                                                const float* __restrict__ P4,
                                                float* __restrict__ M, int D, float h) {
    int idx = blockIdx.x * blockDim.x + threadIdx.x;
    if (idx >= D * D) return;
    int i = idx / D, j = idx % D;
    float c2 = 0.5f * h * h;
    float c3 = h * h * h * (1.0f / 6.0f);
    float c4 = h * h * h * h * (1.0f / 24.0f);
    M[idx] = (i == j ? 1.0f : 0.0f) + h * N_[idx] + c2 * P2[idx] + c3 * P3[idx] + c4 * P4[idx];
}

// ---------------------------------------------------------------------------
// Classic fp32 SGEMM, 64x64 block tile, 4x4 per thread, BK=16.
// C[M,N] = A[M,K] * op(B) (+bias) (relu)
// TRANSB==0: B is [K,N] row-major.  TRANSB==1: B is [N,K] row-major (B^T used).
// Requires M%64==0, N%64==0... (N%4==0 for stores), K%16==0. All shapes here comply.
template <int TRANSB, int RELU, int BIAS>
__global__ __launch_bounds__(256) void gemm_f32(int M, int N, int K,
                                                const float* __restrict__ A,
                                                const float* __restrict__ B,
                                                float* __restrict__ C,
                                                const float* __restrict__ bias) {
    __shared__ float As[BK][BM + 4];
    __shared__ float Bs[BK][BN + 4];
    const int tid = threadIdx.y * 16 + threadIdx.x;
    const int row0 = blockIdx.y * BM;
    const int col0 = blockIdx.x * BN;

    // A-tile load mapping: 256 threads x float4 = 64 rows x 16 k
    const int am = tid >> 2;          // 0..63 (tile row)
    const int akq = (tid & 3) << 2;   // 0,4,8,12 (k quad)
    // B-tile (NN): 16 k-rows x 64 n, float4 along n
    const int bk = tid >> 4;          // 0..15
    const int bn4 = (tid & 15) << 2;  // 0..60
    // B-tile (NT): 64 n-rows x 16 k, float4 along k
    const int bn = tid >> 2;          // 0..63
    const int bkq = (tid & 3) << 2;   // 0,4,8,12

    float acc[4][4] = {};

    for (int k0 = 0; k0 < K; k0 += BK) {
        float4 av = *(const float4*)(A + (size_t)(row0 + am) * K + k0 + akq);
        As[akq + 0][am] = av.x;
        As[akq + 1][am] = av.y;
        As[akq + 2][am] = av.z;
        As[akq + 3][am] = av.w;
        if (TRANSB == 0) {
            float4 bv = *(const float4*)(B + (size_t)(k0 + bk) * N + col0 + bn4);
            *(float4*)(&Bs[bk][bn4]) = bv;  // row stride 68 floats = 272B, 16B-aligned
        } else {
            float4 bv = *(const float4*)(B + (size_t)(col0 + bn) * K + k0 + bkq);
            Bs[bkq + 0][bn] = bv.x;
            Bs[bkq + 1][bn] = bv.y;
            Bs[bkq + 2][bn] = bv.z;
            Bs[bkq + 3][bn] = bv.w;
        }
        __syncthreads();
#pragma unroll
        for (int k = 0; k < BK; ++k) {
            float a[4], b[4];
#pragma unroll
            for (int i = 0; i < 4; ++i) a[i] = As[k][threadIdx.y * 4 + i];
#pragma unroll
            for (int j = 0; j < 4; ++j) b[j] = Bs[k][threadIdx.x * 4 + j];
#pragma unroll
            for (int i = 0; i < 4; ++i)
#pragma unroll
                for (int j = 0; j < 4; ++j) acc[i][j] += a[i] * b[j];
        }
        __syncthreads();
    }

    float bv[4] = {0.f, 0.f, 0.f, 0.f};
    if (BIAS) {
#pragma unroll
        for (int j = 0; j < 4; ++j) bv[j] = bias[col0 + threadIdx.x * 4 + j];
    }
#pragma unroll
    for (int i = 0; i < 4; ++i) {
        float4 v;
        v.x = acc[i][0] + bv[0];
        v.y = acc[i][1] + bv[1];
        v.z = acc[i][2] + bv[2];
        v.w = acc[i][3] + bv[3];
        if (RELU) {
            v.x = fmaxf(v.x, 0.f);
            v.y = fmaxf(v.y, 0.f);
            v.z = fmaxf(v.z, 0.f);
            v.w = fmaxf(v.w, 0.f);
        }
        *(float4*)(C + (size_t)(row0 + threadIdx.y * 4 + i) * N + col0 + threadIdx.x * 4) = v;
    }
}

// ---------------------------------------------------------------------------
extern "C" void kernel_launch(void* const* d_in, const int* in_sizes, int n_in,
                              void* d_out, int out_size, void* d_ws, size_t ws_size,
                              hipStream_t stream) {
    const float* X  = (const float*)d_in[0];  // [B, Dx]
    const float* P  = (const float*)d_in[1];  // [Dz, Dx]
    const float* Am = (const float*)d_in[2];  // [Dz, Dz]
    const float* W1 = (const float*)d_in[3];  // [H, Dz]
    const float* b1 = (const float*)d_in[4];  // [H]
    const float* W2 = (const float*)d_in[5];  // [H, H]
    const float* b2 = (const float*)d_in[6];  // [H]
    const float* W3 = (const float*)d_in[7];  // [Dy, H]
    const float* b3 = (const float*)d_in[8];  // [Dy]
    // d_in[9] = n_steps (==64, fixed for this problem instance)
    float* out = (float*)d_out;               // [B, Dy]

    const float dt = 1.0f / (float)NSTEPS;

    // Workspace layout (floats)
    const size_t S = (size_t)DZ * DZ;  // 262144
    float* ws  = (float*)d_ws;
    float* NT  = ws;            // A^T              [Dz,Dz]
    float* PT  = NT + S;        // P^T              [Dx,Dz]
    float* P2  = PT + S;        // N^2
    float* P3  = P2 + S;        // N^3
    float* P4  = P3 + S;        // N^4
    float* MA  = P4 + S;        // squaring ping
    float* MB  = MA + S;        // squaring pong
    float* C1a = MB + S;        // P^T @ Mtot       [Dx,Dz]
    float* C1t = C1a + S;                   // (P^T Mtot W1^T)^T  [H, Dx]
    float* h1  = C1t + (size_t)HD * DX;     // [B, H]
    float* h2  = h1 + (size_t)BDIM * HD;    // [B, H]
    // total ~80 MB

    dim3 tb(32, 8);
    dim3 tg(DZ / 32, DZ / 32);
    transpose_k<<<tg, tb, 0, stream>>>(Am, NT, DZ);  // N = A^T
    transpose_k<<<tg, tb, 0, stream>>>(P, PT, DZ);   // (Dz==Dx)

    dim3 blk(16, 16);
    auto grid = [](int n, int m) { return dim3(n / BN, m / BM); };

    // N^2, N^3, N^4
    gemm_f32<0, 0, 0><<<grid(DZ, DZ), blk, 0, stream>>>(DZ, DZ, DZ, NT, NT, P2, nullptr);
    gemm_f32<0, 0, 0><<<grid(DZ, DZ), blk, 0, stream>>>(DZ, DZ, DZ, P2, NT, P3, nullptr);
    gemm_f32<0, 0, 0><<<grid(DZ, DZ), blk, 0, stream>>>(DZ, DZ, DZ, P3, NT, P4, nullptr);

    // M_step (RK4 one-step matrix)
    taylor_k<<<(DZ * DZ + 255) / 256, 256, 0, stream>>>(NT, P2, P3, P4, MA, DZ, dt);

    // Mtot = M_step^64 via 6 squarings (log2(NSTEPS)==6)
    float* src = MA;
    float* dst = MB;
    for (int s = 0; s < 6; ++s) {
        gemm_f32<0, 0, 0><<<grid(DZ, DZ), blk, 0, stream>>>(DZ, DZ, DZ, src, src, dst, nullptr);
        float* t = src; src = dst; dst = t;
    }
    // result in src

    // C1a = P^T @ Mtot                        [Dx, Dz]
    gemm_f32<0, 0, 0><<<grid(DZ, DZ), blk, 0, stream>>>(DX, DZ, DZ, PT, src, C1a, nullptr);
    // C1t = W1 @ C1a^T  (== (C1a @ W1^T)^T)   [H, Dx]
    gemm_f32<1, 0, 0><<<grid(DZ, HD), blk, 0, stream>>>(HD, DZ, DZ, W1, C1a, C1t, nullptr);

    // h1 = relu(X @ C1t^T + b1)               [B, H]
    gemm_f32<1, 1, 1><<<grid(HD, BDIM), blk, 0, stream>>>(BDIM, HD, DX, X, C1t, h1, b1);
    // h2 = relu(h1 @ W2^T + b2)               [B, H]
    gemm_f32<1, 1, 1><<<grid(HD, BDIM), blk, 0, stream>>>(BDIM, HD, HD, h1, W2, h2, b2);
    // y = h2 @ W3^T + b3                      [B, Dy]
    gemm_f32<1, 0, 1><<<grid(DY, BDIM), blk, 0, stream>>>(BDIM, DY, HD, h2, W3, out, b3);
}

// Round 2
// 360.940 us; speedup vs baseline: 2.8325x; 2.8325x over previous
//
#include <hip/hip_runtime.h>

// Problem constants (n_steps==64 fixed for this instance).
#define BDIM 4096
#define DX 512
#define DZ 512
#define DY 256
#define HD 2048
#define NSTEPS 64

typedef __attribute__((ext_vector_type(8))) short bf16x8;   // 8 bf16 = 4 VGPRs
typedef __attribute__((ext_vector_type(4))) float f32x4;

__device__ inline unsigned short f2bf(float f) {  // RNE f32 -> bf16
    unsigned u = __float_as_uint(f);
    unsigned r = 0x7FFFu + ((u >> 16) & 1u);
    return (unsigned short)((u + r) >> 16);
}

// async global->LDS, 16B per lane; LDS dest = base + lane*16 (wave-uniform base!)
#define GLDS16(g, l)                                                            \
    __builtin_amdgcn_global_load_lds((const __attribute__((address_space(1))) void*)(g), \
                                     (__attribute__((address_space(3))) void*)(l), 16, 0, 0)

// ---------------------------------------------------------------------------
// f32 -> bf16 elementwise convert (n % 4 == 0)
__global__ __launch_bounds__(256) void cvt_bf16_k(const float* __restrict__ in,
                                                  unsigned short* __restrict__ out, int n) {
    int i = (blockIdx.x * 256 + threadIdx.x) * 4;
    if (i >= n) return;
    float4 v = *(const float4*)(in + i);
    ushort4 o;
    o.x = f2bf(v.x); o.y = f2bf(v.y); o.z = f2bf(v.z); o.w = f2bf(v.w);
    *(ushort4*)(out + i) = o;
}

// ---------------------------------------------------------------------------
// S = I + h*A + h^2/2*A2 + h^3/6*A3 + h^4/24*A4   (RK4 step == Taylor-4, linear f)
__global__ __launch_bounds__(256) void taylor_k(const float* __restrict__ A_,
                                                const float* __restrict__ A2,
                                                const float* __restrict__ A3,
                                                const float* __restrict__ A4,
                                                float* __restrict__ S, int D, float h) {
    int idx = blockIdx.x * 256 + threadIdx.x;
    if (idx >= D * D) return;
    int i = idx / D, j = idx % D;
    float c2 = 0.5f * h * h;
    float c3 = h * h * h * (1.0f / 6.0f);
    float c4 = h * h * h * h * (1.0f / 24.0f);
    S[idx] = (i == j ? 1.0f : 0.0f) + h * A_[idx] + c2 * A2[idx] + c3 * A3[idx] + c4 * A4[idx];
}

// ---------------------------------------------------------------------------
// Small fp32 NN GEMM for the 512x512 chain: C = A @ B, D x D, D%32==0.
// 32x32 tile, 256 threads, 2x2 per thread, 256 blocks at D=512 (full device).
// blockIdx.z selects {A1,B1,C1} or {A2,B2,C2} (batch the A3/A4 pair).
__global__ __launch_bounds__(256) void gemm_nn_small(const float* __restrict__ A1,
                                                     const float* __restrict__ B1,
                                                     float* __restrict__ C1,
                                                     const float* __restrict__ A2p,
                                                     const float* __restrict__ B2p,
                                                     float* __restrict__ C2p, int D) {
    const float* A = (blockIdx.z == 0) ? A1 : A2p;
    const float* B = (blockIdx.z == 0) ? B1 : B2p;
    float* C = (blockIdx.z == 0) ? C1 : C2p;
    __shared__ float As[32][36];  // [m][k], pad 36: 16B-aligned rows, conflict-free
    __shared__ float Bs[32][36];  // [k][n]
    const int tid = threadIdx.x;
    const int lr = tid >> 3;          // 0..31
    const int lc = (tid & 7) * 4;     // 0..28
    const int ty = tid >> 4;          // 0..15 -> rows 2ty,2ty+1
    const int tx = tid & 15;          // 0..15 -> cols 2tx,2tx+1
    const int row0 = blockIdx.y * 32, col0 = blockIdx.x * 32;
    float a00 = 0.f, a01 = 0.f, a10 = 0.f, a11 = 0.f;
    for (int k0 = 0; k0 < D; k0 += 32) {
        *(float4*)&As[lr][lc] = *(const float4*)(A + (size_t)(row0 + lr) * D + k0 + lc);
        *(float4*)&Bs[lr][lc] = *(const float4*)(B + (size_t)(k0 + lr) * D + col0 + lc);
        __syncthreads();
#pragma unroll
        for (int k = 0; k < 32; ++k) {
            float x0 = As[ty * 2 + 0][k], x1 = As[ty * 2 + 1][k];
            float y0 = Bs[k][tx * 2 + 0], y1 = Bs[k][tx * 2 + 1];
            a00 += x0 * y0; a01 += x0 * y1; a10 += x1 * y0; a11 += x1 * y1;
        }
        __syncthreads();
    }
    float* c0 = C + (size_t)(row0 + ty * 2) * D + col0 + tx * 2;
    c0[0] = a00; c0[1] = a01;
    c0[D] = a10; c0[D + 1] = a11;
}

// ---------------------------------------------------------------------------
// bf16 MFMA GEMM (m97-style): C[M,N] = A[M,K] @ B[N,K]^T (+bias) (relu)
// 128x128 block tile, BK=32, 256 threads = 4 waves in 2x2, each wave 64x64
// (4x4 grid of 16x16x32 MFMA). global_load_lds width-16 staging.
// Requires M%128==0, N%128==0, K%32==0.
template <int RELU, int BIAS, int OUT_BF16>
__global__ __launch_bounds__(256) void gemm_bf16(int M, int N, int K,
                                                 const unsigned short* __restrict__ A,
                                                 const unsigned short* __restrict__ B,
                                                 void* __restrict__ C,
                                                 const float* __restrict__ bias) {
    __shared__ unsigned short As[128 * 32];  // row-major [m][k], contiguous (GLDS needs it)
    __shared__ unsigned short Bs[128 * 32];  // row-major [n][k]

    const int tid = threadIdx.x;
    const int lane = tid & 63;
    const int wave = tid >> 6;   // 0..3
    const int wr = wave >> 1;    // wave row 0..1
    const int wc = wave & 1;     // wave col 0..1
    const int row0 = blockIdx.y * 128;
    const int col0 = blockIdx.x * 128;

    // staging: lane i of an instruction covers LDS bytes [i*16, i*16+16)
    const int srow = lane >> 2;         // 0..15: row within 16-row chunk
    const int schunk = (lane & 3) * 8;  // short offset within 32-short row

    f32x4 acc[4][4] = {};

    for (int k0 = 0; k0 < K; k0 += 32) {
        const int r0 = wave * 32;  // this wave stages rows [r0, r0+32)
        GLDS16(A + (size_t)(row0 + r0 + srow) * K + k0 + schunk, &As[r0 * 32]);
        GLDS16(A + (size_t)(row0 + r0 + 16 + srow) * K + k0 + schunk, &As[(r0 + 16) * 32]);
        GLDS16(B + (size_t)(col0 + r0 + srow) * K + k0 + schunk, &Bs[r0 * 32]);
        GLDS16(B + (size_t)(col0 + r0 + 16 + srow) * K + k0 + schunk, &Bs[(r0 + 16) * 32]);
        __syncthreads();  // compiler drains vmcnt before s_barrier

        const int kk = (lane >> 4) * 8;      // k-octet per quad
        const int mbase = wr * 64 + (lane & 15);
        const int nbase = wc * 64 + (lane & 15);
        bf16x8 af[4], bf[4];
#pragma unroll
        for (int t = 0; t < 4; ++t) {
            af[t] = *(const bf16x8*)&As[(mbase + t * 16) * 32 + kk];
            bf[t] = *(const bf16x8*)&Bs[(nbase + t * 16) * 32 + kk];
        }
#pragma unroll
        for (int mt = 0; mt < 4; ++mt)
#pragma unroll
            for (int nt = 0; nt < 4; ++nt)
                acc[mt][nt] = __builtin_amdgcn_mfma_f32_16x16x32_bf16(af[mt], bf[nt],
                                                                      acc[mt][nt], 0, 0, 0);
        __syncthreads();
    }

    // epilogue — C/D layout: col = lane&15, row = (lane>>4)*4 + reg  [m89]
#pragma unroll
    for (int mt = 0; mt < 4; ++mt) {
        const int grow = row0 + wr * 64 + mt * 16 + (lane >> 4) * 4;
#pragma unroll
        for (int nt = 0; nt < 4; ++nt) {
            const int gcol = col0 + wc * 64 + nt * 16 + (lane & 15);
            const float bv = BIAS ? bias[gcol] : 0.0f;
#pragma unroll
            for (int i = 0; i < 4; ++i) {
                float v = acc[mt][nt][i] + bv;
                if (RELU) v = fmaxf(v, 0.0f);
                const size_t off = (size_t)(grow + i) * N + gcol;
                if (OUT_BF16)
                    ((unsigned short*)C)[off] = f2bf(v);
                else
                    ((float*)C)[off] = v;
            }
        }
    }
}

// ---------------------------------------------------------------------------
extern "C" void kernel_launch(void* const* d_in, const int* in_sizes, int n_in,
                              void* d_out, int out_size, void* d_ws, size_t ws_size,
                              hipStream_t stream) {
    const float* X  = (const float*)d_in[0];  // [B, Dx]
    const float* P  = (const float*)d_in[1];  // [Dz, Dx]
    const float* Am = (const float*)d_in[2];  // [Dz, Dz]
    const float* W1 = (const float*)d_in[3];  // [H, Dz]
    const float* b1 = (const float*)d_in[4];
    const float* W2 = (const float*)d_in[5];  // [H, H]
    const float* b2 = (const float*)d_in[6];
    const float* W3 = (const float*)d_in[7];  // [Dy, H]
    const float* b3 = (const float*)d_in[8];
    float* out = (float*)d_out;               // [B, Dy] fp32

    const float h = 1.0f / (float)NSTEPS;
    const size_t S = (size_t)DZ * DZ;

    // ---- workspace carve-up ----
    char* p = (char*)d_ws;
    auto alloc_f = [&](size_t n) { float* r = (float*)p; p += n * 4; return r; };
    auto alloc_h = [&](size_t n) { unsigned short* r = (unsigned short*)p; p += ((n * 2 + 15) & ~15ull); return r; };
    float* A2 = alloc_f(S);
    float* A3 = alloc_f(S);
    float* A4 = alloc_f(S);
    float* MA = alloc_f(S);
    float* MB = alloc_f(S);
    unsigned short* Xb  = alloc_h((size_t)BDIM * DX);
    unsigned short* Pb  = alloc_h((size_t)DZ * DX);
    unsigned short* W1b = alloc_h((size_t)HD * DZ);
    unsigned short* W2b = alloc_h((size_t)HD * HD);
    unsigned short* W3b = alloc_h((size_t)DY * HD);
    unsigned short* Qb  = alloc_h(S);
    unsigned short* z0b = alloc_h((size_t)BDIM * DZ);
    unsigned short* zTb = alloc_h((size_t)BDIM * DZ);
    unsigned short* h1b = alloc_h((size_t)BDIM * HD);
    unsigned short* h2b = alloc_h((size_t)BDIM * HD);

    auto cvt = [&](const float* src, unsigned short* dst, size_t n) {
        cvt_bf16_k<<<dim3((unsigned)((n / 4 + 255) / 256)), 256, 0, stream>>>(src, dst, (int)n);
    };

    // input converts
    cvt(X, Xb, (size_t)BDIM * DX);
    cvt(P, Pb, (size_t)DZ * DX);
    cvt(W1, W1b, (size_t)HD * DZ);
    cvt(W2, W2b, (size_t)HD * HD);
    cvt(W3, W3b, (size_t)DY * HD);

    // z0 = X @ P^T  (NT) -> bf16
    gemm_bf16<0, 0, 1><<<dim3(DZ / 128, BDIM / 128), 256, 0, stream>>>(
        BDIM, DZ, DX, Xb, Pb, z0b, nullptr);

    // ---- fp32 matrix-exponential chain: Q = S^64, S = taylor4(h*A) ----
    dim3 sg(DZ / 32, DZ / 32, 1);
    dim3 sg2(DZ / 32, DZ / 32, 2);
    // A2 = A@A
    gemm_nn_small<<<sg, 256, 0, stream>>>(Am, Am, A2, nullptr, nullptr, nullptr, DZ);
    // A3 = A2@A ; A4 = A2@A2 (batched)
    gemm_nn_small<<<sg2, 256, 0, stream>>>(A2, Am, A3, A2, A2, A4, DZ);
    // S -> MA
    taylor_k<<<(DZ * DZ + 255) / 256, 256, 0, stream>>>(Am, A2, A3, A4, MA, DZ, h);
    // 6 squarings: result back in MA
    float *src = MA, *dst = MB;
    for (int s = 0; s < 6; ++s) {
        gemm_nn_small<<<sg, 256, 0, stream>>>(src, src, dst, nullptr, nullptr, nullptr, DZ);
        float* t = src; src = dst; dst = t;
    }
    // Q (== src == MA) -> bf16; zT = z0 @ Q^T is NT-form directly
    cvt(src, Qb, S);

    // zT = z0 @ Q^T -> bf16
    gemm_bf16<0, 0, 1><<<dim3(DZ / 128, BDIM / 128), 256, 0, stream>>>(
        BDIM, DZ, DZ, z0b, Qb, zTb, nullptr);
    // h1 = relu(zT @ W1^T + b1) -> bf16
    gemm_bf16<1, 1, 1><<<dim3(HD / 128, BDIM / 128), 256, 0, stream>>>(
        BDIM, HD, DZ, zTb, W1b, h1b, b1);
    // h2 = relu(h1 @ W2^T + b2) -> bf16
    gemm_bf16<1, 1, 1><<<dim3(HD / 128, BDIM / 128), 256, 0, stream>>>(
        BDIM, HD, HD, h1b, W2b, h2b, b2);
    // y = h2 @ W3^T + b3 -> fp32 out
    gemm_bf16<0, 1, 0><<<dim3(DY / 128, BDIM / 128), 256, 0, stream>>>(
        BDIM, DY, HD, h2b, W3b, out, b3);
}